// Round 1
// baseline (4983.360 us; speedup 1.0000x reference)
//
#include <hip/hip_runtime.h>

namespace {

constexpr int KSTEPS = 512;
constexpr int NSTATE = 128;
constexpr int NINPUT = 32;
constexpr int HID    = 256;
constexpr int FANIN  = 161;   // 1 + 128 + 32
constexpr int ZPAD   = 168;   // z padded to 2 chunks of 84 (16B-aligned float4 chunks)

__device__ __forceinline__ float fast_tanh(float x) {
  // tanh(x) = 1 - 2/(exp(2x)+1); saturates correctly for |x| large.
  float e2 = __expf(2.0f * x);
  return 1.0f - 2.0f / (e2 + 1.0f);
}

// One block per trajectory (64 blocks). 512 threads:
//  W1 phase: thread t -> hidden row j = t>>1, k-chunk half = t&1 (84 weights each)
//  W2 phase: thread t -> output row o = t>>2, k-quarter q = t&3 (64 weights each)
// Reductions are intra-wave (shfl_xor), so only 2 barriers per stage.
__global__ __launch_bounds__(512, 2)
void ode_tsit5_kernel(const float* __restrict__ ts,
                      const float* __restrict__ y0,
                      const float* __restrict__ us,
                      const float* __restrict__ W1,
                      const float* __restrict__ b1,
                      const float* __restrict__ W2,
                      const float* __restrict__ b2,
                      float* __restrict__ out)
{
  const int b    = blockIdx.x;
  const int t    = threadIdx.x;
  const int j    = t >> 1;   // hidden unit, 0..255
  const int half = t & 1;    // W1 k-chunk
  const int o    = t >> 2;   // state/output row, 0..127
  const int q    = t & 3;    // W2 k-quarter

  __shared__ __align__(16) float z[ZPAD];   // [t, y(128), u(32), pad]
  __shared__ __align__(16) float h[HID];    // tanh activations

  // ---- preload weights into registers (one-time) ----
  float w1[84];
  {
    const float* row = W1 + (long)j * FANIN;
    #pragma unroll
    for (int i = 0; i < 84; ++i) {
      const int k = half * 84 + i;
      w1[i] = (k < FANIN) ? row[k] : 0.0f;
    }
  }
  float w2[64];
  {
    const float* row = W2 + (long)o * HID + q * 64;
    #pragma unroll
    for (int i = 0; i < 64; ++i) w2[i] = row[i];
  }
  const float b1r = b1[j];
  const float b2r = b2[o];

  // Tsit5 tableau (b7 = 0 path)
  constexpr float Cc[5] = {0.161f, 0.327f, 0.9f, 0.9800255409045097f, 1.0f};
  constexpr double CcD[5] = {0.161, 0.327, 0.9, 0.9800255409045097, 1.0};
  constexpr float Af[5][5] = {
    {0.161f, 0.f, 0.f, 0.f, 0.f},
    {-0.008480655492356989f, 0.335480655492357f, 0.f, 0.f, 0.f},
    {2.8971530571054935f, -6.359448489975075f, 4.3622954328695815f, 0.f, 0.f},
    {5.325864828439257f, -11.748883564062828f, 7.4955393428898365f, -0.09249506636175525f, 0.f},
    {5.86145544294642f, -12.92096931784711f, 8.159367898576159f, -0.071584973281401f,
     -0.028269050394068383f}};
  constexpr float Bf[6] = {0.09646076681806523f, 0.01f, 0.4798896504144996f,
                           1.379008574103742f, -3.290069515436081f, 2.324710524099774f};

  // ---- init state for step 0 ----
  float yR = 0.0f;       // y for this thread's o (valid on q==0 threads)
  float ksR[6] = {0.f, 0.f, 0.f, 0.f, 0.f, 0.f};
  if (q == 0) {
    yR = y0[(long)b * NSTATE + o];
    z[1 + o] = yR;
    out[(long)b * KSTEPS * NSTATE + o] = yR;   // row 0 = y0
  }
  if (t == 3) {
    #pragma unroll
    for (int i = FANIN; i < ZPAD; ++i) z[i] = 0.0f;   // zero pad, stays zero
  }

  const float* usb = us + (long)b * KSTEPS * NINPUT;
  const bool is_u = (q == 1) && (o < NINPUT);   // 32 threads own the u-interp lanes
  float u0v = 0.f, u1v = 0.f, hd0v = 0.f;

  for (int i = 0; i < KSTEPS - 1; ++i) {
    const float tcur = ts[i];
    const float dt   = ts[i + 1] - tcur;

    // ---- step prologue: u signal + Hermite derivative (registers) ----
    if (is_u) {
      const int m = o;
      u0v = usb[i * NINPUT + m];
      u1v = usb[(i + 1) * NINPUT + m];
      if (i > 0) {
        const float upv = usb[(i - 1) * NINPUT + m];
        const float dtp = tcur - ts[i - 1];
        hd0v = (u0v - upv) * (dt / dtp);    // h*d0
      } else {
        hd0v = u1v - u0v;                   // d[0] duplicated
      }
      z[1 + NSTATE + m] = u0v;              // theta = 0 -> u0 exactly
    }
    if (t == 2) z[0] = tcur;

    #pragma unroll
    for (int e = 0; e < 6; ++e) {
      __syncthreads();   // z ready (covers prologue writes at e==0)

      // ---- layer 1: h = tanh(W1 z + b1), split k in halves within each lane pair ----
      const float4* zv = (const float4*)(z + half * 84);
      float a0 = 0.f, a1 = 0.f, a2 = 0.f, a3 = 0.f;
      #pragma unroll
      for (int it = 0; it < 21; ++it) {
        const float4 zz = zv[it];
        a0 = __builtin_fmaf(w1[4 * it + 0], zz.x, a0);
        a1 = __builtin_fmaf(w1[4 * it + 1], zz.y, a1);
        a2 = __builtin_fmaf(w1[4 * it + 2], zz.z, a2);
        a3 = __builtin_fmaf(w1[4 * it + 3], zz.w, a3);
      }
      float s1 = (a0 + a1) + (a2 + a3);
      s1 += __shfl_xor(s1, 1);
      if (half == 0) h[j] = fast_tanh(b1r + s1);
      __syncthreads();   // h ready

      // ---- layer 2: f = W2 h + b2, split k in quarters within each lane quad ----
      const float4* hv = (const float4*)(h + q * 64);
      float c0 = 0.f, c1 = 0.f, c2 = 0.f, c3 = 0.f;
      #pragma unroll
      for (int it = 0; it < 16; ++it) {
        const float4 hh = hv[it];
        c0 = __builtin_fmaf(w2[4 * it + 0], hh.x, c0);
        c1 = __builtin_fmaf(w2[4 * it + 1], hh.y, c1);
        c2 = __builtin_fmaf(w2[4 * it + 2], hh.z, c2);
        c3 = __builtin_fmaf(w2[4 * it + 3], hh.w, c3);
      }
      float s2 = (c0 + c1) + (c2 + c3);
      s2 += __shfl_xor(s2, 1);
      s2 += __shfl_xor(s2, 2);

      // ---- combine: tableau state update (registers only) ----
      if (q == 0) {
        ksR[e] = b2r + s2;
        if (e < 5) {
          float acc = 0.f;
          #pragma unroll
          for (int m = 0; m <= e; ++m) acc = __builtin_fmaf(Af[e][m], ksR[m], acc);
          z[1 + o] = __builtin_fmaf(dt, acc, yR);   // ytmp for next stage
        } else {
          float acc = 0.f;
          #pragma unroll
          for (int m = 0; m < 6; ++m) acc = __builtin_fmaf(Bf[m], ksR[m], acc);
          yR = __builtin_fmaf(dt, acc, yR);
          z[1 + o] = yR;                            // base y for next step
          out[((long)b * KSTEPS + (i + 1)) * NSTATE + o] = yR;
        }
      }
      if (e < 5) {
        if (is_u) {
          // u(theta) = cu0*u0 + cu1*u1 + cd0*(h*d0); h*d1 folded as (u1-u0)
          const double th  = CcD[e];
          const float cu0 = (float)(th * th * th - 2.0 * th * th + 1.0);
          const float cu1 = (float)(2.0 * th * th - th * th * th);
          const float cd0 = (float)(th * th * th - 2.0 * th * th + th);
          z[1 + NSTATE + o] = cu0 * u0v + cu1 * u1v + cd0 * hd0v;
        }
        if (t == 2) z[0] = __builtin_fmaf(Cc[e], dt, tcur);
      }
    }
  }
}

} // namespace

extern "C" void kernel_launch(void* const* d_in, const int* in_sizes, int n_in,
                              void* d_out, int out_size, void* d_ws, size_t ws_size,
                              hipStream_t stream) {
  const float* ts = (const float*)d_in[0];
  const float* y0 = (const float*)d_in[1];
  const float* us = (const float*)d_in[2];
  const float* W1 = (const float*)d_in[3];
  const float* b1 = (const float*)d_in[4];
  const float* W2 = (const float*)d_in[5];
  const float* b2 = (const float*)d_in[6];
  float* out = (float*)d_out;
  hipLaunchKernelGGL(ode_tsit5_kernel, dim3(64), dim3(512), 0, stream,
                     ts, y0, us, W1, b1, W2, b2, out);
}

// Round 2
// 3772.776 us; speedup vs baseline: 1.3209x; 1.3209x over previous
//
#include <hip/hip_runtime.h>

namespace {

constexpr int KSTEPS = 512;
constexpr int NSTATE = 128;
constexpr int NINPUT = 32;
constexpr int HID    = 256;
constexpr int FANIN  = 161;    // 1 + 128 + 32

// z padded to 16 chunks of 12 floats (192). Chunk kc covers padded idx [12kc,12kc+12).
constexpr int CH1 = 12, ZP = 192;
// h stored as 16 chunks, stride 20, 16 valid floats each (320). Row j at hp[20*(j>>4)+(j&15)].
constexpr int CH2 = 20, HP = 320;

__device__ __forceinline__ float fast_tanh(float x) {
  float e2 = __expf(2.0f * x);
  return 1.0f - 2.0f / (e2 + 1.0f);
}

// VALU-pipe butterfly add over 16 contiguous lanes (one DPP row).
// xor1 = quad_perm(1,0,3,2)=0xB1, xor2 = quad_perm(2,3,0,1)=0x4E,
// "xor4"-equiv = row_half_mirror(0x141), "xor8"-equiv = row_mirror(0x140).
template <int CTRL>
__device__ __forceinline__ float dpp_add(float x) {
  int y = __builtin_amdgcn_update_dpp(0, __float_as_int(x), CTRL, 0xF, 0xF, false);
  return x + __int_as_float(y);
}
__device__ __forceinline__ float red16(float x) {
  x = dpp_add<0xB1>(x);
  x = dpp_add<0x4E>(x);
  x = dpp_add<0x141>(x);
  x = dpp_add<0x140>(x);
  return x;  // all 16 lanes of the row hold the sum
}

// One block per trajectory. 512 threads = 8 waves.
// Layer1: thread (rg=t>>4, kc=t&15) owns rows rg*8..rg*8+7 x z-chunk kc (12 wide).
// Layer2: thread (og=t>>4, kc2=t&15) owns rows og*4..og*4+3 x h-chunk kc2 (16 wide).
// Reductions: DPP butterfly within each 16-lane row group (no LDS traffic).
__global__ __launch_bounds__(512, 2)
void ode_tsit5_kernel(const float* __restrict__ ts,
                      const float* __restrict__ y0,
                      const float* __restrict__ us,
                      const float* __restrict__ W1,
                      const float* __restrict__ b1,
                      const float* __restrict__ W2,
                      const float* __restrict__ b2,
                      float* __restrict__ out)
{
  const int b   = blockIdx.x;
  const int t   = threadIdx.x;
  const int rg  = t >> 4;    // 0..31
  const int kc  = t & 15;    // 0..15

  __shared__ __align__(16) float z[ZP];
  __shared__ __align__(16) float hp[HP];

  // ---- weights into registers (one-time) ----
  float w1[8][CH1];
  #pragma unroll
  for (int r = 0; r < 8; ++r) {
    const float* row = W1 + (long)(rg * 8 + r) * FANIN;
    #pragma unroll
    for (int i = 0; i < CH1; ++i) {
      const int c = kc * CH1 + i;
      w1[r][i] = (c < FANIN) ? row[c] : 0.0f;
    }
  }
  float w2[4][16];
  #pragma unroll
  for (int r = 0; r < 4; ++r) {
    const float* row = W2 + (long)(rg * 4 + r) * HID + kc * 16;
    #pragma unroll
    for (int i = 0; i < 16; ++i) w2[r][i] = row[i];
  }

  // layer1 tanh/store lane: kc<8 handles hidden row j = rg*8+kc
  const int jrow  = rg * 8 + kc;                       // valid for kc<8
  const float b1r = (kc < 8) ? b1[jrow] : 0.0f;
  const int hpidx = CH2 * (jrow >> 4) + (jrow & 15);   // padded h slot
  // layer2 state lane: kc<4 handles output row o = rg*4+kc
  const int orow  = rg * 4 + kc;                       // valid for kc<4
  const float b2r = (kc < 4) ? b2[orow] : 0.0f;

  // Tsit5 tableau (b7 = 0 path)
  constexpr float Cc[5] = {0.161f, 0.327f, 0.9f, 0.9800255409045097f, 1.0f};
  constexpr double CcD[5] = {0.161, 0.327, 0.9, 0.9800255409045097, 1.0};
  constexpr float Af[5][5] = {
    {0.161f, 0.f, 0.f, 0.f, 0.f},
    {-0.008480655492356989f, 0.335480655492357f, 0.f, 0.f, 0.f},
    {2.8971530571054935f, -6.359448489975075f, 4.3622954328695815f, 0.f, 0.f},
    {5.325864828439257f, -11.748883564062828f, 7.4955393428898365f, -0.09249506636175525f, 0.f},
    {5.86145544294642f, -12.92096931784711f, 8.159367898576159f, -0.071584973281401f,
     -0.028269050394068383f}};
  constexpr float Bf[6] = {0.09646076681806523f, 0.01f, 0.4798896504144996f,
                           1.379008574103742f, -3.290069515436081f, 2.324710524099774f};

  // ---- init ----
  float yR = 0.0f, ksR[6] = {0.f, 0.f, 0.f, 0.f, 0.f, 0.f};
  if (kc < 4) {
    yR = y0[(long)b * NSTATE + orow];
    z[1 + orow] = yR;
    out[(long)b * KSTEPS * NSTATE + orow] = yR;
  }
  if (t < ZP - FANIN) z[FANIN + t] = 0.0f;   // zero pad once; never rewritten

  // u-interp lanes: kc==8, m = rg (32 lanes)
  const bool is_u = (kc == 8);
  const int  m    = rg;
  const float* usb = us + (long)b * KSTEPS * NINPUT;
  float u0v = 0.f, u1v = 0.f, uprev = 0.f;
  if (is_u) u0v = usb[m];
  float tcur = ts[0];
  float dtp  = 1.0f;   // dt of previous step (unused at i==0)
  if (is_u) z[1 + NSTATE + m] = u0v;
  if (t == 9) z[0] = tcur;

  for (int i = 0; i < KSTEPS - 1; ++i) {
    const float tnext = ts[i + 1];
    const float dt    = tnext - tcur;

    float hd0v = 0.f;
    if (is_u) {
      u1v = usb[(i + 1) * NINPUT + m];
      hd0v = (i == 0) ? (u1v - u0v) : (u0v - uprev) * (dt / dtp);
    }

    #pragma unroll
    for (int e = 0; e < 6; ++e) {
      __syncthreads();   // z ready

      // ---- layer 1: 8 rows x 12-wide z chunk ----
      const float4* zv = (const float4*)(z + kc * CH1);
      const float4 z0 = zv[0], z1 = zv[1], z2 = zv[2];
      float acc[8];
      #pragma unroll
      for (int r = 0; r < 8; ++r) {
        float a = w1[r][0] * z0.x;
        a = __builtin_fmaf(w1[r][1], z0.y, a);
        a = __builtin_fmaf(w1[r][2], z0.z, a);
        a = __builtin_fmaf(w1[r][3], z0.w, a);
        a = __builtin_fmaf(w1[r][4], z1.x, a);
        a = __builtin_fmaf(w1[r][5], z1.y, a);
        a = __builtin_fmaf(w1[r][6], z1.z, a);
        a = __builtin_fmaf(w1[r][7], z1.w, a);
        a = __builtin_fmaf(w1[r][8], z2.x, a);
        a = __builtin_fmaf(w1[r][9], z2.y, a);
        a = __builtin_fmaf(w1[r][10], z2.z, a);
        a = __builtin_fmaf(w1[r][11], z2.w, a);
        acc[r] = a;
      }
      #pragma unroll
      for (int r = 0; r < 8; ++r) acc[r] = red16(acc[r]);
      if (kc < 8) hp[hpidx] = fast_tanh(b1r + acc[kc]);
      __syncthreads();   // hp ready

      // ---- layer 2: 4 rows x 16-wide h chunk ----
      const float4* hv = (const float4*)(hp + kc * CH2);
      const float4 h0 = hv[0], h1 = hv[1], h2 = hv[2], h3 = hv[3];
      float a2[4];
      #pragma unroll
      for (int r = 0; r < 4; ++r) {
        float c = w2[r][0] * h0.x;
        c = __builtin_fmaf(w2[r][1],  h0.y, c);
        c = __builtin_fmaf(w2[r][2],  h0.z, c);
        c = __builtin_fmaf(w2[r][3],  h0.w, c);
        c = __builtin_fmaf(w2[r][4],  h1.x, c);
        c = __builtin_fmaf(w2[r][5],  h1.y, c);
        c = __builtin_fmaf(w2[r][6],  h1.z, c);
        c = __builtin_fmaf(w2[r][7],  h1.w, c);
        c = __builtin_fmaf(w2[r][8],  h2.x, c);
        c = __builtin_fmaf(w2[r][9],  h2.y, c);
        c = __builtin_fmaf(w2[r][10], h2.z, c);
        c = __builtin_fmaf(w2[r][11], h2.w, c);
        c = __builtin_fmaf(w2[r][12], h3.x, c);
        c = __builtin_fmaf(w2[r][13], h3.y, c);
        c = __builtin_fmaf(w2[r][14], h3.z, c);
        c = __builtin_fmaf(w2[r][15], h3.w, c);
        a2[r] = c;
      }
      #pragma unroll
      for (int r = 0; r < 4; ++r) a2[r] = red16(a2[r]);

      // ---- tableau combine on state lanes (kc<4) ----
      if (kc < 4) {
        ksR[e] = b2r + a2[kc];
        if (e < 5) {
          float acm = 0.f;
          #pragma unroll
          for (int mm = 0; mm <= e; ++mm) acm = __builtin_fmaf(Af[e][mm], ksR[mm], acm);
          z[1 + orow] = __builtin_fmaf(dt, acm, yR);
        } else {
          float acm = 0.f;
          #pragma unroll
          for (int mm = 0; mm < 6; ++mm) acm = __builtin_fmaf(Bf[mm], ksR[mm], acm);
          yR = __builtin_fmaf(dt, acm, yR);
          z[1 + orow] = yR;
          out[((long)b * KSTEPS + (i + 1)) * NSTATE + orow] = yR;
        }
      }
      if (e < 5) {
        if (is_u) {
          const double th = CcD[e];
          const float cu0 = (float)(th * th * th - 2.0 * th * th + 1.0);
          const float cu1 = (float)(2.0 * th * th - th * th * th);
          const float cd0 = (float)(th * th * th - 2.0 * th * th + th);
          z[1 + NSTATE + m] = cu0 * u0v + cu1 * u1v + cd0 * hd0v;
        }
        if (t == 9) z[0] = __builtin_fmaf(Cc[e], dt, tcur);
      } else {
        if (is_u) z[1 + NSTATE + m] = u1v;   // theta=0 of next step is u[i+1]
        if (t == 9) z[0] = tnext;
      }
    }

    // ---- roll step state ----
    if (is_u) { uprev = u0v; u0v = u1v; }
    dtp  = dt;
    tcur = tnext;
  }
}

} // namespace

extern "C" void kernel_launch(void* const* d_in, const int* in_sizes, int n_in,
                              void* d_out, int out_size, void* d_ws, size_t ws_size,
                              hipStream_t stream) {
  const float* ts = (const float*)d_in[0];
  const float* y0 = (const float*)d_in[1];
  const float* us = (const float*)d_in[2];
  const float* W1 = (const float*)d_in[3];
  const float* b1 = (const float*)d_in[4];
  const float* W2 = (const float*)d_in[5];
  const float* b2 = (const float*)d_in[6];
  float* out = (float*)d_out;
  hipLaunchKernelGGL(ode_tsit5_kernel, dim3(64), dim3(512), 0, stream,
                     ts, y0, us, W1, b1, W2, b2, out);
}

// Round 3
// 2633.228 us; speedup vs baseline: 1.8925x; 1.4328x over previous
//
#include <hip/hip_runtime.h>

namespace {

typedef _Float16 h2 __attribute__((ext_vector_type(2)));

constexpr int KSTEPS = 512;
constexpr int NSTATE = 128;
constexpr int NINPUT = 32;
constexpr int HID    = 256;
constexpr int FANIN  = 161;

// z16 layout (f16): [y 0..127 | u 128..159 | t at 160 | zero pad 161..191]
constexpr int ZLEN = 192;
// hs: 8 chunks, stride 40 f16 (32 valid + 8 pad) -> bank-conflict-free b128 reads
constexpr int HCH  = 40;
constexpr int HLEN = 8 * HCH;

__device__ __forceinline__ float fdot2(h2 a, h2 b, float c) {
#if __has_builtin(__builtin_amdgcn_fdot2)
  return __builtin_amdgcn_fdot2(a, b, c, false);
#else
  return c + (float)a[0] * (float)b[0] + (float)a[1] * (float)b[1];
#endif
}

__device__ __forceinline__ float fast_tanh(float x) {
  float e2 = __expf(2.0f * x);
  return 1.0f - 2.0f / (e2 + 1.0f);
}

template <int CTRL>
__device__ __forceinline__ float dpp_add(float x) {
  int y = __builtin_amdgcn_update_dpp(0, __float_as_int(x), CTRL, 0xF, 0xF, false);
  return x + __int_as_float(y);
}
// sum across 8 consecutive lanes (xor1, xor2, half-row mirror)
__device__ __forceinline__ float red8(float x) {
  x = dpp_add<0xB1>(x);
  x = dpp_add<0x4E>(x);
  x = dpp_add<0x141>(x);
  return x;
}

union F4 { float4 f; h2 h[4]; };

// One block per trajectory (64 blocks, 512 thr = 8 waves).
// Layer1: thread (g=t>>3, kc=t&7) owns hidden rows 4g..4g+3 x z-chunk kc (24 f16).
// Layer2: same thread owns state rows 2g..2g+1 x h-chunk kc (32 f16).
// v_dot2_f32_f16: 2 MACs/inst, fp32 accumulate. Reductions: 3-step DPP over 8 lanes.
__global__ __launch_bounds__(512, 2)
void ode_tsit5_kernel(const float* __restrict__ ts,
                      const float* __restrict__ y0,
                      const float* __restrict__ us,
                      const float* __restrict__ W1,
                      const float* __restrict__ b1,
                      const float* __restrict__ W2,
                      const float* __restrict__ b2,
                      float* __restrict__ out)
{
  const int b  = blockIdx.x;
  const int t  = threadIdx.x;
  const int g  = t >> 3;   // 0..63
  const int kc = t & 7;    // 0..7

  __shared__ __align__(16) _Float16 z16[ZLEN];
  __shared__ __align__(16) _Float16 hs[HLEN];

  // ---- pack weights into f16-pair registers (one-time) ----
  // z position p maps to W1 column: p<160 -> p+1 (y then u), p==160 -> 0 (t), else pad 0.
  h2 w1[4][12];
  #pragma unroll
  for (int r = 0; r < 4; ++r) {
    const float* row = W1 + (long)(4 * g + r) * FANIN;
    #pragma unroll
    for (int i = 0; i < 12; ++i) {
      const int p0 = 24 * kc + 2 * i;
      const int p1 = p0 + 1;
      const float f0 = (p0 < 160) ? row[p0 + 1] : ((p0 == 160) ? row[0] : 0.0f);
      const float f1 = (p1 < 160) ? row[p1 + 1] : ((p1 == 160) ? row[0] : 0.0f);
      w1[r][i] = h2{(_Float16)f0, (_Float16)f1};
    }
  }
  h2 w2[2][16];
  #pragma unroll
  for (int r = 0; r < 2; ++r) {
    const float* row = W2 + (long)(2 * g + r) * HID + 32 * kc;
    #pragma unroll
    for (int i = 0; i < 16; ++i)
      w2[r][i] = h2{(_Float16)row[2 * i], (_Float16)row[2 * i + 1]};
  }

  const int   jrow = 4 * g + kc;                     // layer1 store row (kc<4)
  const float b1r  = (kc < 4) ? b1[jrow] : 0.0f;
  const int   hidx = HCH * (jrow >> 5) + (jrow & 31);
  const int   orow = 2 * g + kc;                     // layer2 row (kc<2)
  const float b2r  = (kc < 2) ? b2[orow] : 0.0f;

  // Tsit5 tableau (b7 = 0 path)
  constexpr float Cc[5] = {0.161f, 0.327f, 0.9f, 0.9800255409045097f, 1.0f};
  constexpr double CcD[5] = {0.161, 0.327, 0.9, 0.9800255409045097, 1.0};
  constexpr float Af[5][5] = {
    {0.161f, 0.f, 0.f, 0.f, 0.f},
    {-0.008480655492356989f, 0.335480655492357f, 0.f, 0.f, 0.f},
    {2.8971530571054935f, -6.359448489975075f, 4.3622954328695815f, 0.f, 0.f},
    {5.325864828439257f, -11.748883564062828f, 7.4955393428898365f, -0.09249506636175525f, 0.f},
    {5.86145544294642f, -12.92096931784711f, 8.159367898576159f, -0.071584973281401f,
     -0.028269050394068383f}};
  constexpr float Bf[6] = {0.09646076681806523f, 0.01f, 0.4798896504144996f,
                           1.379008574103742f, -3.290069515436081f, 2.324710524099774f};

  // ---- init ----
  float yR = 0.0f, ksR[6] = {0.f, 0.f, 0.f, 0.f, 0.f, 0.f};
  if (kc < 2) {
    yR = y0[(long)b * NSTATE + orow];
    z16[orow] = (_Float16)yR;
    out[(long)b * KSTEPS * NSTATE + orow] = yR;
  }
  if (t < ZLEN - FANIN - 30) {}   // (no-op; keep structure simple)
  if (t < 31) z16[161 + t] = (_Float16)0.0f;   // zero pad, never rewritten

  const bool is_u = (kc == 2) && (g < 32);
  const int  m    = g;
  const float* usb = us + (long)b * KSTEPS * NINPUT;
  float u0v = 0.f, u1v = 0.f, uprev = 0.f;
  if (is_u) { u0v = usb[m]; z16[128 + m] = (_Float16)u0v; }
  float tcur = ts[0];
  float dtp  = 1.0f;
  if (t == 4) z16[160] = (_Float16)tcur;

  for (int i = 0; i < KSTEPS - 1; ++i) {
    const float tnext = ts[i + 1];
    const float dt    = tnext - tcur;

    float hd0v = 0.f;
    if (is_u) {
      u1v = usb[(i + 1) * NINPUT + m];
      hd0v = (i == 0) ? (u1v - u0v) : (u0v - uprev) * (dt / dtp);
    }

    #pragma unroll
    for (int e = 0; e < 6; ++e) {
      __syncthreads();   // z16 ready

      // ---- layer 1: 4 rows x 24-f16 z chunk, dot2 ----
      const float4* zp = (const float4*)(z16 + 24 * kc);
      F4 zc0, zc1, zc2;
      zc0.f = zp[0]; zc1.f = zp[1]; zc2.f = zp[2];
      float acc[4];
      #pragma unroll
      for (int r = 0; r < 4; ++r) {
        float a = fdot2(w1[r][0], zc0.h[0], 0.0f);
        a = fdot2(w1[r][1],  zc0.h[1], a);
        a = fdot2(w1[r][2],  zc0.h[2], a);
        a = fdot2(w1[r][3],  zc0.h[3], a);
        a = fdot2(w1[r][4],  zc1.h[0], a);
        a = fdot2(w1[r][5],  zc1.h[1], a);
        a = fdot2(w1[r][6],  zc1.h[2], a);
        a = fdot2(w1[r][7],  zc1.h[3], a);
        a = fdot2(w1[r][8],  zc2.h[0], a);
        a = fdot2(w1[r][9],  zc2.h[1], a);
        a = fdot2(w1[r][10], zc2.h[2], a);
        a = fdot2(w1[r][11], zc2.h[3], a);
        acc[r] = a;
      }
      #pragma unroll
      for (int r = 0; r < 4; ++r) acc[r] = red8(acc[r]);
      if (kc < 4) hs[hidx] = (_Float16)fast_tanh(b1r + acc[kc]);
      __syncthreads();   // hs ready

      // ---- layer 2: 2 rows x 32-f16 h chunk, dot2 ----
      const float4* hp4 = (const float4*)(hs + HCH * kc);
      F4 hc0, hc1, hc2, hc3;
      hc0.f = hp4[0]; hc1.f = hp4[1]; hc2.f = hp4[2]; hc3.f = hp4[3];
      float a2[2];
      #pragma unroll
      for (int r = 0; r < 2; ++r) {
        float c = fdot2(w2[r][0], hc0.h[0], 0.0f);
        c = fdot2(w2[r][1],  hc0.h[1], c);
        c = fdot2(w2[r][2],  hc0.h[2], c);
        c = fdot2(w2[r][3],  hc0.h[3], c);
        c = fdot2(w2[r][4],  hc1.h[0], c);
        c = fdot2(w2[r][5],  hc1.h[1], c);
        c = fdot2(w2[r][6],  hc1.h[2], c);
        c = fdot2(w2[r][7],  hc1.h[3], c);
        c = fdot2(w2[r][8],  hc2.h[0], c);
        c = fdot2(w2[r][9],  hc2.h[1], c);
        c = fdot2(w2[r][10], hc2.h[2], c);
        c = fdot2(w2[r][11], hc2.h[3], c);
        c = fdot2(w2[r][12], hc3.h[0], c);
        c = fdot2(w2[r][13], hc3.h[1], c);
        c = fdot2(w2[r][14], hc3.h[2], c);
        c = fdot2(w2[r][15], hc3.h[3], c);
        a2[r] = c;
      }
      #pragma unroll
      for (int r = 0; r < 2; ++r) a2[r] = red8(a2[r]);

      // ---- tableau combine on state lanes (kc<2) ----
      if (kc < 2) {
        ksR[e] = b2r + a2[kc];
        if (e < 5) {
          float acm = 0.f;
          #pragma unroll
          for (int mm = 0; mm <= e; ++mm) acm = __builtin_fmaf(Af[e][mm], ksR[mm], acm);
          z16[orow] = (_Float16)__builtin_fmaf(dt, acm, yR);
        } else {
          float acm = 0.f;
          #pragma unroll
          for (int mm = 0; mm < 6; ++mm) acm = __builtin_fmaf(Bf[mm], ksR[mm], acm);
          yR = __builtin_fmaf(dt, acm, yR);
          z16[orow] = (_Float16)yR;
          out[((long)b * KSTEPS + (i + 1)) * NSTATE + orow] = yR;
        }
      }
      if (e < 5) {
        if (is_u) {
          const double th = CcD[e];
          const float cu0 = (float)(th * th * th - 2.0 * th * th + 1.0);
          const float cu1 = (float)(2.0 * th * th - th * th * th);
          const float cd0 = (float)(th * th * th - 2.0 * th * th + th);
          z16[128 + m] = (_Float16)(cu0 * u0v + cu1 * u1v + cd0 * hd0v);
        }
        if (t == 4) z16[160] = (_Float16)__builtin_fmaf(Cc[e], dt, tcur);
      } else {
        if (is_u) z16[128 + m] = (_Float16)u1v;
        if (t == 4) z16[160] = (_Float16)tnext;
      }
    }

    if (is_u) { uprev = u0v; u0v = u1v; }
    dtp  = dt;
    tcur = tnext;
  }
}

} // namespace

extern "C" void kernel_launch(void* const* d_in, const int* in_sizes, int n_in,
                              void* d_out, int out_size, void* d_ws, size_t ws_size,
                              hipStream_t stream) {
  const float* ts = (const float*)d_in[0];
  const float* y0 = (const float*)d_in[1];
  const float* us = (const float*)d_in[2];
  const float* W1 = (const float*)d_in[3];
  const float* b1 = (const float*)d_in[4];
  const float* W2 = (const float*)d_in[5];
  const float* b2 = (const float*)d_in[6];
  float* out = (float*)d_out;
  hipLaunchKernelGGL(ode_tsit5_kernel, dim3(64), dim3(512), 0, stream,
                     ts, y0, us, W1, b1, W2, b2, out);
}